// Round 14
// baseline (229.795 us; speedup 1.0000x reference)
//
#include <hip/hip_runtime.h>
#include <hip/hip_cooperative_groups.h>
#include <math.h>

namespace cg = cooperative_groups;

typedef __bf16 bf16x8 __attribute__((ext_vector_type(8)));
typedef float f32x4 __attribute__((ext_vector_type(4)));

#define B_SZ 512
#define IN_F 342
#define HID  512
#define OUT_F 311

// ---------------------------------------------------------------------------
// Weight transpose+convert+interleave (one 64x64 tile per call):
//  JOB0: T0[h*4+c][i] = W0[c][i][h]  (2048 x 384, i>=342 -> 0)
//  JOB1: T1[h*4+c][k] = W1[c][k][h]  (2048 x 512)
//  JOB2: T2[n*4+c][k] = W2[c][k][n]  (1280 x 512, n>=311 -> 0)
// Interleaved rows n'=h*4+c put the 4 c-slices of an output in one MFMA
// lane-quad -> coefficient reduction is 2 shfl_xor in the GEMM epilogue.
// ---------------------------------------------------------------------------
template <int JOB>
__device__ void wt_transpose(const float* __restrict__ W, __bf16* __restrict__ T,
                             int t, __bf16 (*tile)[66]) {
  constexpr int KP   = (JOB == 0) ? 384 : 512;   // dest row length (padded k)
  constexpr int KWF  = (JOB == 0) ? IN_F : HID;  // W k extent
  constexpr int NC   = (JOB == 2) ? OUT_F : HID; // W col extent
  constexpr int NSUB = (JOB == 2) ? 320 : 512;   // dest rows per c (pre-ilv)
  constexpr int KT   = KP / 64;
  const int r0 = (t / KT) * 64, k0 = (t % KT) * 64;
  const int tid = threadIdx.x;
  const int rl = tid & 63;
  const int c = r0 / NSUB;          // uniform per tile (64 | NSUB)
  const int nbase = r0 - c * NSUB;
#pragma unroll
  for (int jj = 0; jj < 16; ++jj) {
    int kl = (tid >> 6) + jj * 4;
    int k = k0 + kl;
    int n = nbase + rl;
    float v = 0.0f;
    if ((JOB != 0 || k < KWF) && (JOB != 2 || n < NC))
      v = W[((size_t)c * KWF + k) * NC + n];
    tile[rl][kl] = (__bf16)v;
  }
  __syncthreads();
  int row = tid >> 2, o0 = (tid & 3) * 16;
  bf16x8 v0 = *(const bf16x8*)&tile[row][o0];
  bf16x8 v1 = *(const bf16x8*)&tile[row][o0 + 8];
  int g = (nbase + row) * 4 + c;    // interleaved dest row
  __bf16* dst = T + (size_t)g * KP + k0 + o0;
  *(bf16x8*)dst = v0;
  *(bf16x8*)(dst + 8) = v1;
}

// ---------------------------------------------------------------------------
// Streaming bf16 MFMA GEMM (R12-validated): 32x64 tile, full K (T=6/8),
// 2-deep statically-named reg prefetch, in-register quad-reduce epilogue.
// ---------------------------------------------------------------------------
template <int LAYER>
__device__ void gemm_body(int nx, int my, const __bf16* __restrict__ A,
                          const __bf16* __restrict__ BT,
                          const float* __restrict__ bias,
                          const float* __restrict__ coef,
                          void* __restrict__ outv,
                          __bf16* __restrict__ Als, __bf16* __restrict__ Bls) {
  constexpr int KA = (LAYER == 0) ? 384 : 512;
  constexpr int T = KA / 64;        // 6 or 8 (even)
  constexpr int LDT = 72;

  const int tid = threadIdx.x;
  const int l = tid & 63;
  const int wave = tid >> 6;
  const int wm = wave >> 1, wn = wave & 1;
  const int lr = l & 15, lk = l >> 4;
  const int m0 = my * 32;
  const int n0 = nx * 64;

  const int ar = tid >> 3, ao = tid & 7;        // A: row 0..31, octet 0..7
  const int br = tid >> 2, bo = (tid & 3) * 2;  // B: row 0..63, octets bo,bo+1

  const __bf16* Ap = A + (size_t)(m0 + ar) * KA + ao * 8;
  const __bf16* Bp = BT + (size_t)(n0 + br) * KA + bo * 8;

  bf16x8 a0_, b0_, b1_;   // phase 0
  bf16x8 a1_, b2_, b3_;   // phase 1
  f32x4 acc[2] = {};

  auto load0 = [&](int t) {
    a0_ = *(const bf16x8*)&Ap[t * 64];
    b0_ = *(const bf16x8*)&Bp[t * 64];
    b1_ = *(const bf16x8*)&Bp[t * 64 + 8];
  };
  auto load1 = [&](int t) {
    a1_ = *(const bf16x8*)&Ap[t * 64];
    b2_ = *(const bf16x8*)&Bp[t * 64];
    b3_ = *(const bf16x8*)&Bp[t * 64 + 8];
  };
  auto store0 = [&]() {
    *(bf16x8*)&Als[ar * LDT + ao * 8] = a0_;
    *(bf16x8*)&Bls[br * LDT + bo * 8] = b0_;
    *(bf16x8*)&Bls[br * LDT + bo * 8 + 8] = b1_;
  };
  auto store1 = [&]() {
    *(bf16x8*)&Als[ar * LDT + ao * 8] = a1_;
    *(bf16x8*)&Bls[br * LDT + bo * 8] = b2_;
    *(bf16x8*)&Bls[br * LDT + bo * 8 + 8] = b3_;
  };
  auto compute = [&]() {
#pragma unroll
    for (int kk = 0; kk < 64; kk += 32) {
      bf16x8 af = *(const bf16x8*)&Als[(wm * 16 + lr) * LDT + kk + lk * 8];
      bf16x8 bg[2];
#pragma unroll
      for (int j = 0; j < 2; ++j)
        bg[j] = *(const bf16x8*)&Bls[(wn * 32 + j * 16 + lr) * LDT + kk + lk * 8];
#pragma unroll
      for (int j = 0; j < 2; ++j)
        acc[j] = __builtin_amdgcn_mfma_f32_16x16x32_bf16(af, bg[j], acc[j], 0, 0, 0);
    }
  };

  load0(0);
  load1(1);
  for (int t = 0; t < T; t += 2) {
    __syncthreads();
    store0();
    __syncthreads();
    if (t + 2 < T) load0(t + 2);
    compute();
    __syncthreads();
    store1();
    __syncthreads();
    if (t + 3 < T) load1(t + 3);
    compute();
  }

  // ---- fused epilogue: quad holds the 4 c-partials of (gm, hn) ----
  const int cl = l & 3;
#pragma unroll
  for (int j = 0; j < 2; ++j) {
    int gnp = n0 + wn * 32 + j * 16 + lr;
    int hn = gnp >> 2;                       // h (L0/L1) or n (L2)
    float bv;
    if (LAYER == 2) bv = (hn < OUT_F) ? bias[cl * OUT_F + hn] : 0.0f;
    else            bv = bias[cl * HID + hn];
#pragma unroll
    for (int r = 0; r < 4; ++r) {
      int gm = m0 + wm * 16 + lk * 4 + r;
      float cf = coef[gm * 4 + cl];
      float v = cf * (acc[j][r] + bv);
      v += __shfl_xor(v, 1);
      v += __shfl_xor(v, 2);                 // quad sum over c
      if (LAYER == 2) {
        if (cl == 0 && hn < OUT_F)
          ((float*)outv)[(size_t)gm * OUT_F + hn] = v;
      } else {
        if (cl == 0) {
          float e = (v > 0.0f) ? v : expm1f(v);
          ((__bf16*)outv)[(size_t)gm * HID + hn] = (__bf16)e;
        }
      }
    }
  }
}

// ---------------------------------------------------------------------------
// ONE cooperative kernel, 512 blocks x 256 threads (co-resident: 2 blk/CU).
// Phase S: 625 jobs strided (transposes, x->bf16, coef). grid.sync between
// phases provides cross-XCD visibility (no manual fences).
// ---------------------------------------------------------------------------
__global__ __launch_bounds__(256) void fused_kernel(
    const float* __restrict__ p, const float* __restrict__ x,
    const float* __restrict__ W0, const float* __restrict__ b0,
    const float* __restrict__ W1, const float* __restrict__ b1,
    const float* __restrict__ W2, const float* __restrict__ b2,
    float* __restrict__ out, float* __restrict__ coef,
    __bf16* __restrict__ A0, __bf16* __restrict__ T0,
    __bf16* __restrict__ T1, __bf16* __restrict__ T2,
    __bf16* __restrict__ E1, __bf16* __restrict__ E2) {
  cg::grid_group grid = cg::this_grid();
  __shared__ __attribute__((aligned(16))) unsigned char smem[14336];
  __bf16* Als = (__bf16*)smem;                 // 32*72*2 = 4608 B
  __bf16* Bls = (__bf16*)(smem + 4608);        // 64*72*2 = 9216 B
  __bf16 (*tile)[66] = (__bf16(*)[66])smem;    // 8448 B (phase S only)

  const int bid = blockIdx.x;
  const int tid = threadIdx.x;

  // ---- phase S ----
  for (int j = bid; j < 625; j += 512) {
    if (j < 192)      wt_transpose<0>(W0, T0, j, tile);
    else if (j < 448) wt_transpose<1>(W1, T1, j - 192, tile);
    else if (j < 608) wt_transpose<2>(W2, T2, j - 448, tile);
    else if (j < 624) {
      int base = (j - 608) * 32;
      for (int e = tid; e < 32 * 384; e += 256) {
        int m = base + e / 384, i = e - (e / 384) * 384;
        A0[(size_t)m * 384 + i] =
            (i < IN_F) ? (__bf16)x[(size_t)m * IN_F + i] : (__bf16)0.0f;
      }
    } else {
      for (int b = tid; b < B_SZ; b += 256) {
        float p4 = p[b] * 4.0f;
        float mu = p4 - floorf(p4);
        int i1 = ((int)p4) & 3;
        float mu2 = mu * mu, mu3 = mu2 * mu;
        float c0 = -0.5f * mu3 + mu2 - 0.5f * mu;
        float c1 =  1.5f * mu3 - 2.5f * mu2 + 1.0f;
        float c2 = -1.5f * mu3 + 2.0f * mu2 + 0.5f * mu;
        float c3 =  0.5f * mu3 - 0.5f * mu2;
        float arr[4];
        arr[(i1 + 3) & 3] = c0;
        arr[i1]           = c1;
        arr[(i1 + 1) & 3] = c2;
        arr[(i1 + 2) & 3] = c3;
        coef[b * 4 + 0] = arr[0];
        coef[b * 4 + 1] = arr[1];
        coef[b * 4 + 2] = arr[2];
        coef[b * 4 + 3] = arr[3];
      }
    }
    __syncthreads();   // tile reuse safety between strided jobs
  }

  grid.sync();
  gemm_body<0>(bid & 31, bid >> 5, A0, T0, b0, coef, E1, Als, Bls);
  grid.sync();
  gemm_body<1>(bid & 31, bid >> 5, E1, T1, b1, coef, E2, Als, Bls);
  grid.sync();
  if (bid < 320)
    gemm_body<2>(bid % 20, bid / 20, E2, T2, b2, coef, out, Als, Bls);
}

extern "C" void kernel_launch(void* const* d_in, const int* in_sizes, int n_in,
                              void* d_out, int out_size, void* d_ws, size_t ws_size,
                              hipStream_t stream) {
  const float* p  = (const float*)d_in[0];
  const float* x  = (const float*)d_in[1];
  const float* W0 = (const float*)d_in[2];
  const float* b0 = (const float*)d_in[3];
  const float* W1 = (const float*)d_in[4];
  const float* b1 = (const float*)d_in[5];
  const float* W2 = (const float*)d_in[6];
  const float* b2 = (const float*)d_in[7];
  float* out = (float*)d_out;

  char* w = (char*)d_ws;
  float*  coef = (float*)w;   w += 8192;
  __bf16* A0   = (__bf16*)w;  w += (size_t)B_SZ * 384 * 2;   // 384 KB
  __bf16* T0   = (__bf16*)w;  w += (size_t)2048 * 384 * 2;   // 1.5 MB
  __bf16* T1   = (__bf16*)w;  w += (size_t)2048 * 512 * 2;   // 2 MB
  __bf16* T2   = (__bf16*)w;  w += (size_t)1280 * 512 * 2;   // 1.25 MB
  __bf16* E1   = (__bf16*)w;  w += (size_t)B_SZ * HID * 2;   // 512 KB
  __bf16* E2   = (__bf16*)w;  w += (size_t)B_SZ * HID * 2;   // 512 KB

  void* args[] = {(void*)&p,  (void*)&x,  (void*)&W0, (void*)&b0,
                  (void*)&W1, (void*)&b1, (void*)&W2, (void*)&b2,
                  (void*)&out, (void*)&coef, (void*)&A0, (void*)&T0,
                  (void*)&T1, (void*)&T2, (void*)&E1, (void*)&E2};
  (void)hipLaunchCooperativeKernel((void*)fused_kernel, dim3(512), dim3(256),
                                   args, 0, stream);
}

// Round 15
// 43.408 us; speedup vs baseline: 5.2938x; 5.2938x over previous
//
#include <hip/hip_runtime.h>
#include <math.h>

typedef __bf16 bf16x8 __attribute__((ext_vector_type(8)));
typedef float f32x4 __attribute__((ext_vector_type(4)));

#define B_SZ 512
#define IN_F 342
#define HID  512
#define OUT_F 311

// ---------------------------------------------------------------------------
// Weight transpose+convert+interleave (one 64x64 tile per call):
//  JOB0: T0[h*4+c][i] = W0[c][i][h]  (2048 x 384, i>=342 -> 0)
//  JOB1: T1[h*4+c][k] = W1[c][k][h]  (2048 x 512)
//  JOB2: T2[n*4+c][k] = W2[c][k][n]  (1280 x 512, n>=311 -> 0)
// Interleaved rows n'=h*4+c put the 4 c-slices of an output in one MFMA
// lane-quad -> coefficient reduction is 2 shfl_xor in the GEMM epilogue.
// ---------------------------------------------------------------------------
template <int JOB>
__device__ void wt_transpose(const float* __restrict__ W, __bf16* __restrict__ T,
                             int t) {
  constexpr int KP   = (JOB == 0) ? 384 : 512;   // dest row length (padded k)
  constexpr int KWF  = (JOB == 0) ? IN_F : HID;  // W k extent
  constexpr int NC   = (JOB == 2) ? OUT_F : HID; // W col extent
  constexpr int NSUB = (JOB == 2) ? 320 : 512;   // dest rows per c (pre-ilv)
  constexpr int KT   = KP / 64;
  const int r0 = (t / KT) * 64, k0 = (t % KT) * 64;
  __shared__ __bf16 tile[64][66];
  const int tid = threadIdx.x;
  const int rl = tid & 63;
  const int c = r0 / NSUB;          // uniform per tile (64 | NSUB)
  const int nbase = r0 - c * NSUB;
#pragma unroll
  for (int jj = 0; jj < 16; ++jj) {
    int kl = (tid >> 6) + jj * 4;
    int k = k0 + kl;
    int n = nbase + rl;
    float v = 0.0f;
    if ((JOB != 0 || k < KWF) && (JOB != 2 || n < NC))
      v = W[((size_t)c * KWF + k) * NC + n];
    tile[rl][kl] = (__bf16)v;
  }
  __syncthreads();
  int row = tid >> 2, o0 = (tid & 3) * 16;
  bf16x8 v0 = *(const bf16x8*)&tile[row][o0];
  bf16x8 v1 = *(const bf16x8*)&tile[row][o0 + 8];
  int g = (nbase + row) * 4 + c;    // interleaved dest row
  __bf16* dst = T + (size_t)g * KP + k0 + o0;
  *(bf16x8*)dst = v0;
  *(bf16x8*)(dst + 8) = v1;
}

// ---------------------------------------------------------------------------
// Streaming bf16 MFMA GEMM (R12-validated): 32x64 tile, full K (T=6/8),
// 2-deep statically-named reg prefetch, in-register quad-reduce epilogue.
// ---------------------------------------------------------------------------
template <int LAYER>
__device__ void gemm_body(int nx, int my, const __bf16* __restrict__ A,
                          const __bf16* __restrict__ BT,
                          const float* __restrict__ bias,
                          const float* __restrict__ coef,
                          void* __restrict__ outv) {
  constexpr int KA = (LAYER == 0) ? 384 : 512;
  constexpr int T = KA / 64;        // 6 or 8 (even)
  constexpr int LDT = 72;
  __shared__ __bf16 Als[32 * LDT];
  __shared__ __bf16 Bls[64 * LDT];

  const int tid = threadIdx.x;
  const int l = tid & 63;
  const int wave = tid >> 6;
  const int wm = wave >> 1, wn = wave & 1;
  const int lr = l & 15, lk = l >> 4;
  const int m0 = my * 32;
  const int n0 = nx * 64;

  const int ar = tid >> 3, ao = tid & 7;        // A: row 0..31, octet 0..7
  const int br = tid >> 2, bo = (tid & 3) * 2;  // B: row 0..63, octets bo,bo+1

  const __bf16* Ap = A + (size_t)(m0 + ar) * KA + ao * 8;
  const __bf16* Bp = BT + (size_t)(n0 + br) * KA + bo * 8;

  bf16x8 a0_, b0_, b1_;   // phase 0
  bf16x8 a1_, b2_, b3_;   // phase 1
  f32x4 acc[2] = {};

  auto load0 = [&](int t) {
    a0_ = *(const bf16x8*)&Ap[t * 64];
    b0_ = *(const bf16x8*)&Bp[t * 64];
    b1_ = *(const bf16x8*)&Bp[t * 64 + 8];
  };
  auto load1 = [&](int t) {
    a1_ = *(const bf16x8*)&Ap[t * 64];
    b2_ = *(const bf16x8*)&Bp[t * 64];
    b3_ = *(const bf16x8*)&Bp[t * 64 + 8];
  };
  auto store0 = [&]() {
    *(bf16x8*)&Als[ar * LDT + ao * 8] = a0_;
    *(bf16x8*)&Bls[br * LDT + bo * 8] = b0_;
    *(bf16x8*)&Bls[br * LDT + bo * 8 + 8] = b1_;
  };
  auto store1 = [&]() {
    *(bf16x8*)&Als[ar * LDT + ao * 8] = a1_;
    *(bf16x8*)&Bls[br * LDT + bo * 8] = b2_;
    *(bf16x8*)&Bls[br * LDT + bo * 8 + 8] = b3_;
  };
  auto compute = [&]() {
#pragma unroll
    for (int kk = 0; kk < 64; kk += 32) {
      bf16x8 af = *(const bf16x8*)&Als[(wm * 16 + lr) * LDT + kk + lk * 8];
      bf16x8 bg[2];
#pragma unroll
      for (int j = 0; j < 2; ++j)
        bg[j] = *(const bf16x8*)&Bls[(wn * 32 + j * 16 + lr) * LDT + kk + lk * 8];
#pragma unroll
      for (int j = 0; j < 2; ++j)
        acc[j] = __builtin_amdgcn_mfma_f32_16x16x32_bf16(af, bg[j], acc[j], 0, 0, 0);
    }
  };

  load0(0);
  load1(1);
  for (int t = 0; t < T; t += 2) {
    __syncthreads();
    store0();
    __syncthreads();
    if (t + 2 < T) load0(t + 2);
    compute();
    __syncthreads();
    store1();
    __syncthreads();
    if (t + 3 < T) load1(t + 3);
    compute();
  }

  // ---- fused epilogue: quad holds the 4 c-partials of (gm, hn) ----
  const int cl = l & 3;
#pragma unroll
  for (int j = 0; j < 2; ++j) {
    int gnp = n0 + wn * 32 + j * 16 + lr;
    int hn = gnp >> 2;                       // h (L0/L1) or n (L2)
    float bv;
    if (LAYER == 2) bv = (hn < OUT_F) ? bias[cl * OUT_F + hn] : 0.0f;
    else            bv = bias[cl * HID + hn];
#pragma unroll
    for (int r = 0; r < 4; ++r) {
      int gm = m0 + wm * 16 + lk * 4 + r;
      float cf = coef[gm * 4 + cl];
      float v = cf * (acc[j][r] + bv);
      v += __shfl_xor(v, 1);
      v += __shfl_xor(v, 2);                 // quad sum over c
      if (LAYER == 2) {
        if (cl == 0 && hn < OUT_F)
          ((float*)outv)[(size_t)gm * OUT_F + hn] = v;
      } else {
        if (cl == 0) {
          float e = (v > 0.0f) ? v : expm1f(v);
          ((__bf16*)outv)[(size_t)gm * HID + hn] = (__bf16)e;
        }
      }
    }
  }
}

// ---------------------------------------------------------------------------
// setup (625 blocks, one job each — full-width BW burst):
//  0..191 WT0, 192..447 WT1, 448..607 WT2, 608..623 A0=bf16(x), 624 coef.
// ---------------------------------------------------------------------------
__global__ __launch_bounds__(256) void setup_kernel(
    const float* __restrict__ p, const float* __restrict__ x,
    const float* __restrict__ W0, const float* __restrict__ W1,
    const float* __restrict__ W2, float* __restrict__ coef,
    __bf16* __restrict__ A0, __bf16* __restrict__ T0,
    __bf16* __restrict__ T1, __bf16* __restrict__ T2) {
  int bid = blockIdx.x, tid = threadIdx.x;
  if (bid < 192)      { wt_transpose<0>(W0, T0, bid); return; }
  if (bid < 448)      { wt_transpose<1>(W1, T1, bid - 192); return; }
  if (bid < 608)      { wt_transpose<2>(W2, T2, bid - 448); return; }
  if (bid < 624) {
    int base = (bid - 608) * 32;
    for (int e = tid; e < 32 * 384; e += 256) {
      int m = base + e / 384, i = e - (e / 384) * 384;
      A0[(size_t)m * 384 + i] =
          (i < IN_F) ? (__bf16)x[(size_t)m * IN_F + i] : (__bf16)0.0f;
    }
    return;
  }
  for (int b = tid; b < B_SZ; b += 256) {
    float p4 = p[b] * 4.0f;
    float mu = p4 - floorf(p4);
    int i1 = ((int)p4) & 3;
    float mu2 = mu * mu, mu3 = mu2 * mu;
    float c0 = -0.5f * mu3 + mu2 - 0.5f * mu;
    float c1 =  1.5f * mu3 - 2.5f * mu2 + 1.0f;
    float c2 = -1.5f * mu3 + 2.0f * mu2 + 0.5f * mu;
    float c3 =  0.5f * mu3 - 0.5f * mu2;
    float arr[4];
    arr[(i1 + 3) & 3] = c0;
    arr[i1]           = c1;
    arr[(i1 + 1) & 3] = c2;
    arr[(i1 + 2) & 3] = c3;
    coef[b * 4 + 0] = arr[0];
    coef[b * 4 + 1] = arr[1];
    coef[b * 4 + 2] = arr[2];
    coef[b * 4 + 3] = arr[3];
  }
}

__global__ __launch_bounds__(256) void g0_kernel(
    const __bf16* __restrict__ A0, const __bf16* __restrict__ T0,
    const float* __restrict__ b0, const float* __restrict__ coef,
    __bf16* __restrict__ E1) {
  gemm_body<0>(blockIdx.x, blockIdx.y, A0, T0, b0, coef, E1);
}

__global__ __launch_bounds__(256) void g1_kernel(
    const __bf16* __restrict__ E1, const __bf16* __restrict__ T1,
    const float* __restrict__ b1, const float* __restrict__ coef,
    __bf16* __restrict__ E2) {
  gemm_body<1>(blockIdx.x, blockIdx.y, E1, T1, b1, coef, E2);
}

__global__ __launch_bounds__(256) void g2_kernel(
    const __bf16* __restrict__ E2, const __bf16* __restrict__ T2,
    const float* __restrict__ b2, const float* __restrict__ coef,
    float* __restrict__ out) {
  gemm_body<2>(blockIdx.x, blockIdx.y, E2, T2, b2, coef, out);
}

extern "C" void kernel_launch(void* const* d_in, const int* in_sizes, int n_in,
                              void* d_out, int out_size, void* d_ws, size_t ws_size,
                              hipStream_t stream) {
  const float* p  = (const float*)d_in[0];
  const float* x  = (const float*)d_in[1];
  const float* W0 = (const float*)d_in[2];
  const float* b0 = (const float*)d_in[3];
  const float* W1 = (const float*)d_in[4];
  const float* b1 = (const float*)d_in[5];
  const float* W2 = (const float*)d_in[6];
  const float* b2 = (const float*)d_in[7];
  float* out = (float*)d_out;

  char* w = (char*)d_ws;
  float*  coef = (float*)w;   w += 8192;
  __bf16* A0   = (__bf16*)w;  w += (size_t)B_SZ * 384 * 2;   // 384 KB
  __bf16* T0   = (__bf16*)w;  w += (size_t)2048 * 384 * 2;   // 1.5 MB
  __bf16* T1   = (__bf16*)w;  w += (size_t)2048 * 512 * 2;   // 2 MB
  __bf16* T2   = (__bf16*)w;  w += (size_t)1280 * 512 * 2;   // 1.25 MB
  __bf16* E1   = (__bf16*)w;  w += (size_t)B_SZ * HID * 2;   // 512 KB
  __bf16* E2   = (__bf16*)w;  w += (size_t)B_SZ * HID * 2;   // 512 KB

  setup_kernel<<<625, 256, 0, stream>>>(p, x, W0, W1, W2, coef, A0, T0, T1, T2);
  g0_kernel<<<dim3(32, 16), 256, 0, stream>>>(A0, T0, b0, coef, E1);
  g1_kernel<<<dim3(32, 16), 256, 0, stream>>>(E1, T1, b1, coef, E2);
  g2_kernel<<<dim3(20, 16), 256, 0, stream>>>(E2, T2, b2, coef, out);
}

// Round 16
// 42.454 us; speedup vs baseline: 5.4128x; 1.0225x over previous
//
#include <hip/hip_runtime.h>
#include <math.h>

typedef __bf16 bf16x8 __attribute__((ext_vector_type(8)));
typedef float f32x4 __attribute__((ext_vector_type(4)));

#define B_SZ 512
#define IN_F 342
#define HID  512
#define OUT_F 311

// ---------------------------------------------------------------------------
// Weight transpose+convert+interleave (one 64x64 tile per call):
//  JOB0: T0[h*4+c][i] = W0[c][i][h]  (2048 x 384, i>=342 -> 0)
//  JOB1: T1[h*4+c][k] = W1[c][k][h]  (2048 x 512)
//  JOB2: T2[n*4+c][k] = W2[c][k][n]  (1280 x 512, n>=311 -> 0)
// Interleaved rows n'=h*4+c put the 4 c-slices of an output in one MFMA
// lane-quad -> coefficient reduction is 2 shfl_xor in the GEMM epilogue.
// ---------------------------------------------------------------------------
template <int JOB>
__device__ void wt_transpose(const float* __restrict__ W, __bf16* __restrict__ T,
                             int t) {
  constexpr int KP   = (JOB == 0) ? 384 : 512;   // dest row length (padded k)
  constexpr int KWF  = (JOB == 0) ? IN_F : HID;  // W k extent
  constexpr int NC   = (JOB == 2) ? OUT_F : HID; // W col extent
  constexpr int NSUB = (JOB == 2) ? 320 : 512;   // dest rows per c (pre-ilv)
  constexpr int KT   = KP / 64;
  const int r0 = (t / KT) * 64, k0 = (t % KT) * 64;
  __shared__ __bf16 tile[64][66];
  const int tid = threadIdx.x;
  const int rl = tid & 63;
  const int c = r0 / NSUB;          // uniform per tile (64 | NSUB)
  const int nbase = r0 - c * NSUB;
#pragma unroll
  for (int jj = 0; jj < 16; ++jj) {
    int kl = (tid >> 6) + jj * 4;
    int k = k0 + kl;
    int n = nbase + rl;
    float v = 0.0f;
    if ((JOB != 0 || k < KWF) && (JOB != 2 || n < NC))
      v = W[((size_t)c * KWF + k) * NC + n];
    tile[rl][kl] = (__bf16)v;
  }
  __syncthreads();
  int row = tid >> 2, o0 = (tid & 3) * 16;
  bf16x8 v0 = *(const bf16x8*)&tile[row][o0];
  bf16x8 v1 = *(const bf16x8*)&tile[row][o0 + 8];
  int g = (nbase + row) * 4 + c;    // interleaved dest row
  __bf16* dst = T + (size_t)g * KP + k0 + o0;
  *(bf16x8*)dst = v0;
  *(bf16x8*)(dst + 8) = v1;
}

// ---------------------------------------------------------------------------
// Streaming bf16 MFMA GEMM, BK=128, double-buffered LDS, ONE barrier per
// K-tile (T = 3 or 4 tiles total). Per tile: issue next-tile global loads
// (6x b128) -> compute current LDS buffer (12 ds_read_b128 + 8 MFMA) ->
// store next buffer -> barrier. Statically-named regs (rule #20).
// Epilogue: in-register quad-reduce over interleaved c (R12/R15-validated).
// ---------------------------------------------------------------------------
template <int LAYER>
__device__ void gemm_body(int nx, int my, const __bf16* __restrict__ A,
                          const __bf16* __restrict__ BT,
                          const float* __restrict__ bias,
                          const float* __restrict__ coef,
                          void* __restrict__ outv) {
  constexpr int KA = (LAYER == 0) ? 384 : 512;
  constexpr int T = KA / 128;       // 3 or 4
  constexpr int LDA = 136;          // 128 + 8 elems
  constexpr int ASZ = 32 * LDA;
  constexpr int BSZ = 64 * LDA;
  __shared__ __bf16 Als[2 * ASZ];   // 17 KB
  __shared__ __bf16 Bls[2 * BSZ];   // 34 KB

  const int tid = threadIdx.x;
  const int l = tid & 63;
  const int wave = tid >> 6;
  const int wm = wave >> 1, wn = wave & 1;
  const int lr = l & 15, lk = l >> 4;
  const int m0 = my * 32;
  const int n0 = nx * 64;

  const int ar = tid >> 3, ao = tid & 7;   // A: row 0..31, octet 0..7 (+8)
  const int br = tid >> 2, bo = tid & 3;   // B: row 0..63, octet pairs

  const __bf16* Ap = A + (size_t)(m0 + ar) * KA + ao * 8;
  const __bf16* Bp = BT + (size_t)(n0 + br) * KA + bo * 16;

  bf16x8 a0_, a1_, b0_, b1_, b2_, b3_;
  f32x4 acc[2] = {};

  auto loadreg = [&](int t) {
    a0_ = *(const bf16x8*)&Ap[t * 128];
    a1_ = *(const bf16x8*)&Ap[t * 128 + 64];
    b0_ = *(const bf16x8*)&Bp[t * 128];
    b1_ = *(const bf16x8*)&Bp[t * 128 + 8];
    b2_ = *(const bf16x8*)&Bp[t * 128 + 64];
    b3_ = *(const bf16x8*)&Bp[t * 128 + 72];
  };
  auto storeLDS = [&](int ph) {
    __bf16* Ac = Als + ph * ASZ;
    __bf16* Bc = Bls + ph * BSZ;
    *(bf16x8*)&Ac[ar * LDA + ao * 8] = a0_;
    *(bf16x8*)&Ac[ar * LDA + ao * 8 + 64] = a1_;
    *(bf16x8*)&Bc[br * LDA + bo * 16] = b0_;
    *(bf16x8*)&Bc[br * LDA + bo * 16 + 8] = b1_;
    *(bf16x8*)&Bc[br * LDA + bo * 16 + 64] = b2_;
    *(bf16x8*)&Bc[br * LDA + bo * 16 + 72] = b3_;
  };
  auto compute = [&](int ph) {
    const __bf16* Ac = Als + ph * ASZ;
    const __bf16* Bc = Bls + ph * BSZ;
#pragma unroll
    for (int kk = 0; kk < 128; kk += 32) {
      bf16x8 af = *(const bf16x8*)&Ac[(wm * 16 + lr) * LDA + kk + lk * 8];
      bf16x8 bg[2];
#pragma unroll
      for (int j = 0; j < 2; ++j)
        bg[j] = *(const bf16x8*)&Bc[(wn * 32 + j * 16 + lr) * LDA + kk + lk * 8];
#pragma unroll
      for (int j = 0; j < 2; ++j)
        acc[j] = __builtin_amdgcn_mfma_f32_16x16x32_bf16(af, bg[j], acc[j], 0, 0, 0);
    }
  };

  loadreg(0);
  storeLDS(0);
  __syncthreads();
  for (int t = 0; t < T; ++t) {
    if (t + 1 < T) loadreg(t + 1);   // issue early: latency hides under compute
    compute(t & 1);
    if (t + 1 < T) {
      storeLDS((t + 1) & 1);         // waits vmcnt internally (compiler)
      __syncthreads();               // buf[(t+1)&1] ready; buf[t&1] reads done
    }
  }

  // ---- fused epilogue: quad holds the 4 c-partials of (gm, hn) ----
  const int cl = l & 3;
#pragma unroll
  for (int j = 0; j < 2; ++j) {
    int gnp = n0 + wn * 32 + j * 16 + lr;
    int hn = gnp >> 2;                       // h (L0/L1) or n (L2)
    float bv;
    if (LAYER == 2) bv = (hn < OUT_F) ? bias[cl * OUT_F + hn] : 0.0f;
    else            bv = bias[cl * HID + hn];
#pragma unroll
    for (int r = 0; r < 4; ++r) {
      int gm = m0 + wm * 16 + lk * 4 + r;
      float cf = coef[gm * 4 + cl];
      float v = cf * (acc[j][r] + bv);
      v += __shfl_xor(v, 1);
      v += __shfl_xor(v, 2);                 // quad sum over c
      if (LAYER == 2) {
        if (cl == 0 && hn < OUT_F)
          ((float*)outv)[(size_t)gm * OUT_F + hn] = v;
      } else {
        if (cl == 0) {
          float e = (v > 0.0f) ? v : expm1f(v);
          ((__bf16*)outv)[(size_t)gm * HID + hn] = (__bf16)e;
        }
      }
    }
  }
}

// ---------------------------------------------------------------------------
// setup (625 blocks, one job each — full-width BW burst):
//  0..191 WT0, 192..447 WT1, 448..607 WT2, 608..623 A0=bf16(x), 624 coef.
// ---------------------------------------------------------------------------
__global__ __launch_bounds__(256) void setup_kernel(
    const float* __restrict__ p, const float* __restrict__ x,
    const float* __restrict__ W0, const float* __restrict__ W1,
    const float* __restrict__ W2, float* __restrict__ coef,
    __bf16* __restrict__ A0, __bf16* __restrict__ T0,
    __bf16* __restrict__ T1, __bf16* __restrict__ T2) {
  int bid = blockIdx.x, tid = threadIdx.x;
  if (bid < 192)      { wt_transpose<0>(W0, T0, bid); return; }
  if (bid < 448)      { wt_transpose<1>(W1, T1, bid - 192); return; }
  if (bid < 608)      { wt_transpose<2>(W2, T2, bid - 448); return; }
  if (bid < 624) {
    int base = (bid - 608) * 32;
    for (int e = tid; e < 32 * 384; e += 256) {
      int m = base + e / 384, i = e - (e / 384) * 384;
      A0[(size_t)m * 384 + i] =
          (i < IN_F) ? (__bf16)x[(size_t)m * IN_F + i] : (__bf16)0.0f;
    }
    return;
  }
  for (int b = tid; b < B_SZ; b += 256) {
    float p4 = p[b] * 4.0f;
    float mu = p4 - floorf(p4);
    int i1 = ((int)p4) & 3;
    float mu2 = mu * mu, mu3 = mu2 * mu;
    float c0 = -0.5f * mu3 + mu2 - 0.5f * mu;
    float c1 =  1.5f * mu3 - 2.5f * mu2 + 1.0f;
    float c2 = -1.5f * mu3 + 2.0f * mu2 + 0.5f * mu;
    float c3 =  0.5f * mu3 - 0.5f * mu2;
    float arr[4];
    arr[(i1 + 3) & 3] = c0;
    arr[i1]           = c1;
    arr[(i1 + 1) & 3] = c2;
    arr[(i1 + 2) & 3] = c3;
    coef[b * 4 + 0] = arr[0];
    coef[b * 4 + 1] = arr[1];
    coef[b * 4 + 2] = arr[2];
    coef[b * 4 + 3] = arr[3];
  }
}

__global__ __launch_bounds__(256) void g0_kernel(
    const __bf16* __restrict__ A0, const __bf16* __restrict__ T0,
    const float* __restrict__ b0, const float* __restrict__ coef,
    __bf16* __restrict__ E1) {
  gemm_body<0>(blockIdx.x, blockIdx.y, A0, T0, b0, coef, E1);
}

__global__ __launch_bounds__(256) void g1_kernel(
    const __bf16* __restrict__ E1, const __bf16* __restrict__ T1,
    const float* __restrict__ b1, const float* __restrict__ coef,
    __bf16* __restrict__ E2) {
  gemm_body<1>(blockIdx.x, blockIdx.y, E1, T1, b1, coef, E2);
}

__global__ __launch_bounds__(256) void g2_kernel(
    const __bf16* __restrict__ E2, const __bf16* __restrict__ T2,
    const float* __restrict__ b2, const float* __restrict__ coef,
    float* __restrict__ out) {
  gemm_body<2>(blockIdx.x, blockIdx.y, E2, T2, b2, coef, out);
}

extern "C" void kernel_launch(void* const* d_in, const int* in_sizes, int n_in,
                              void* d_out, int out_size, void* d_ws, size_t ws_size,
                              hipStream_t stream) {
  const float* p  = (const float*)d_in[0];
  const float* x  = (const float*)d_in[1];
  const float* W0 = (const float*)d_in[2];
  const float* b0 = (const float*)d_in[3];
  const float* W1 = (const float*)d_in[4];
  const float* b1 = (const float*)d_in[5];
  const float* W2 = (const float*)d_in[6];
  const float* b2 = (const float*)d_in[7];
  float* out = (float*)d_out;

  char* w = (char*)d_ws;
  float*  coef = (float*)w;   w += 8192;
  __bf16* A0   = (__bf16*)w;  w += (size_t)B_SZ * 384 * 2;   // 384 KB
  __bf16* T0   = (__bf16*)w;  w += (size_t)2048 * 384 * 2;   // 1.5 MB
  __bf16* T1   = (__bf16*)w;  w += (size_t)2048 * 512 * 2;   // 2 MB
  __bf16* T2   = (__bf16*)w;  w += (size_t)1280 * 512 * 2;   // 1.25 MB
  __bf16* E1   = (__bf16*)w;  w += (size_t)B_SZ * HID * 2;   // 512 KB
  __bf16* E2   = (__bf16*)w;  w += (size_t)B_SZ * HID * 2;   // 512 KB

  setup_kernel<<<625, 256, 0, stream>>>(p, x, W0, W1, W2, coef, A0, T0, T1, T2);
  g0_kernel<<<dim3(32, 16), 256, 0, stream>>>(A0, T0, b0, coef, E1);
  g1_kernel<<<dim3(32, 16), 256, 0, stream>>>(E1, T1, b1, coef, E2);
  g2_kernel<<<dim3(20, 16), 256, 0, stream>>>(E2, T2, b2, coef, out);
}